// Round 12
// baseline (391.860 us; speedup 1.0000x reference)
//
#include <hip/hip_runtime.h>
#include <hip/hip_bf16.h>

// CoreAttention (ChatGLM GQA fallback) — swapped-operand 32x32x16 bf16 MFMA
// flash attention. Round 12: head-OCTET blocks — 8 waves = 8 heads (same
// kv-group) x the SAME 32 q rows; K/V/mask staged once per block via
// global_load_lds from pre-swizzled images; waves 0-3 stage K+mask, 4-7 stage
// V. Same per-wave code as r11 but 2x waves/SIMD (occupancy play).
// Q pre-scaled by SCALE*log2e; no softmax shift (shift-invariant, bounded).
// B=2, H=32, G=2, Q=KV=2048, D=128, fp32 in/out.

constexpr int Bn = 2, Hn = 32, Gn = 2, Qn = 2048, KVn = 2048, Dn = 128;
constexpr int WAVES = 8, QBLK = 32, HO = 8;           // 32 q rows, 8 heads/blk
constexpr int KVB = 32, NT = KVn / KVB;               // 64 kv tiles
constexpr int NT32 = KVn / 32;
constexpr float SCALE = 0.08838834764831843f;         // 1/sqrt(128)
constexpr float L2E = 1.4426950408889634f;
constexpr float SCALE2 = SCALE * L2E;

// ws: K images (2 MiB) then V images (2 MiB); needs ws >= 4 MiB.
// K image (per bg): kv*256 + ((4*dp) ^ ((kv&15)<<4))   [256B rows, bf16]
// V image (per bg, 32-kv subtile): (d<<6) + ((vkp*4) ^ slot(d)),
//   slot(d) = (((d>>3)^(d>>1))&3)<<4
constexpr size_t WSK_BYTES = (size_t)Bn * Gn * KVn * 256;   // 2 MiB

typedef __attribute__((ext_vector_type(16))) float f32x16;
typedef __attribute__((ext_vector_type(8))) __bf16 bf16x8;

__device__ __forceinline__ unsigned pk2(float a, float b) {
  union { __bf16 h[2]; unsigned u; } x;
  x.h[0] = (__bf16)a; x.h[1] = (__bf16)b;
  return x.u;
}

__global__ __launch_bounds__(256)
void prepack(const float* __restrict__ Kg, const float* __restrict__ Vg,
             char* __restrict__ wsK, char* __restrict__ wsV) {
  const int i = blockIdx.x * 256 + threadIdx.x;   // [0, 524288)
  {  // K pair: dp = d/2
    const int dp = i & 63, kv = (i >> 6) & (KVn - 1), bg = i >> 17;
    const float* src = Kg + ((size_t)bg * KVn + kv) * Dn + 2 * dp;
    const unsigned pr = pk2(src[0], src[1]);
    const size_t off = (size_t)bg * (KVn * 256) + (size_t)kv * 256
                       + ((4 * dp) ^ ((kv & 15) << 4));
    *(unsigned*)(wsK + off) = pr;
  }
  {  // V^T pair: (kv=2vkp, 2vkp+1) at row d, 32-kv subtile t
    const int d = i & 127, vg = (i >> 7) & 1023, bg = i >> 17;
    const int t = vg >> 4, vkp = vg & 15;
    const float* src = Vg + ((size_t)bg * KVn + t * 32 + 2 * vkp) * Dn + d;
    const unsigned pr = pk2(src[0], src[Dn]);
    const int slot = (((d >> 3) ^ (d >> 1)) & 3) << 4;
    const size_t off = ((size_t)bg * NT32 + t) * 8192 + (d << 6)
                       + ((vkp * 4) ^ slot);
    *(unsigned*)(wsV + off) = pr;
  }
}

__global__ __launch_bounds__(512, 4)
void attn_fwd(const float* __restrict__ Qg, const float* __restrict__ Mg,
              const char* __restrict__ wsK, const char* __restrict__ wsV,
              float* __restrict__ Og) {
  __shared__ __align__(16) short Ks[2][KVB * Dn];    // 8KB x2
  __shared__ __align__(16) short Vt[2][Dn * KVB];    // 8KB x2
  __shared__ __align__(16) float Ms[2][QBLK * KVB];  // 4KB x2 (swizzled rows)

  const int tid = threadIdx.x;
  const int lane = tid & 63, w = tid >> 6;           // w in [0,8)
  const int hi = lane >> 5, ln = lane & 31;
  const int qb = blockIdx.x * QBLK, ho = blockIdx.y, b = blockIdx.z;
  const int h = ho * HO + w;                         // wave's head
  const int g = ho >> 1, bg = b * Gn + g;            // octet shares g

  // ---- Q B-fragments, PRE-SCALED: aq[ks][j] = Q[h][qb+ln][ks*16+hi*8+j]*SCALE2
  bf16x8 aq[8];
  {
    const float* qr = Qg + ((size_t)(b * Hn + h) * Qn + qb + ln) * Dn + hi * 8;
#pragma unroll
    for (int ks = 0; ks < 8; ++ks) {
      float4 f0 = *(const float4*)(qr + ks * 16);
      float4 f1 = *(const float4*)(qr + ks * 16 + 4);
      union { unsigned u[4]; bf16x8 b; } t;
      t.u[0] = pk2(f0.x * SCALE2, f0.y * SCALE2);
      t.u[1] = pk2(f0.z * SCALE2, f0.w * SCALE2);
      t.u[2] = pk2(f1.x * SCALE2, f1.y * SCALE2);
      t.u[3] = pk2(f1.z * SCALE2, f1.w * SCALE2);
      aq[ks] = t.b;
    }
  }

  const char* wsKb = wsK + (size_t)bg * (KVn * 256);
  const char* wsVb = wsV + (size_t)bg * (KVn * 256);
  // mask stage geometry (waves 0-3): wave w covers rows w*8..w*8+7 (128B each)
  const int mr = (w & 3) * 8 + (lane >> 3);          // q row within tile
  const int mc = (lane & 7) << 4;                    // 16B slot within row
  const char* mSrcBase = (const char*)Mg + (size_t)(b * Qn + qb + mr) * (KVn * 4)
                         + (mc ^ ((mr & 7) << 4));   // pre-swizzled source

  // waves 0-3: K (2 gll) + mask (1 gll); waves 4-7: V (2 gll)
  auto stage = [&](int tile, int buf) {
    if (w < 4) {
      const char* sk = wsKb + (size_t)tile * 8192 + w * 2048 + lane * 16;
      char* dk = (char*)Ks[buf] + w * 2048;
      __builtin_amdgcn_global_load_lds(
          (const __attribute__((address_space(1))) void*)sk,
          (__attribute__((address_space(3))) void*)dk, 16, 0, 0);
      __builtin_amdgcn_global_load_lds(
          (const __attribute__((address_space(1))) void*)(sk + 1024),
          (__attribute__((address_space(3))) void*)(dk + 1024), 16, 0, 0);
      const char* sm = mSrcBase + tile * 128;
      char* dm = (char*)Ms[buf] + w * 1024;
      __builtin_amdgcn_global_load_lds(
          (const __attribute__((address_space(1))) void*)sm,
          (__attribute__((address_space(3))) void*)dm, 16, 0, 0);
    } else {
      const int wv = w - 4;
      const char* sv = wsVb + (size_t)tile * 8192 + wv * 2048 + lane * 16;
      char* dv = (char*)Vt[buf] + wv * 2048;
      __builtin_amdgcn_global_load_lds(
          (const __attribute__((address_space(1))) void*)sv,
          (__attribute__((address_space(3))) void*)dv, 16, 0, 0);
      __builtin_amdgcn_global_load_lds(
          (const __attribute__((address_space(1))) void*)(sv + 1024),
          (__attribute__((address_space(3))) void*)(dv + 1024), 16, 0, 0);
    }
  };

  f32x16 o[4];
#pragma unroll
  for (int nt = 0; nt < 4; ++nt)
#pragma unroll
    for (int e = 0; e < 16; ++e) o[nt][e] = 0.0f;
  float lsum = 0.0f;

  // ---- prologue ----
  stage(0, 0);
  __syncthreads();

  const int ksw = (ln & 15) << 4;
  const int msw = (ln & 7) << 4;

  for (int t = 0; t < NT; ++t) {
    const int cur = t & 1;
    const int tn = (t + 1 < NT) ? t + 1 : t;

    stage(tn, cur ^ 1);     // prefetch next tile (gll; covered by tile body)
    __builtin_amdgcn_sched_barrier(0);

    // ---- QK^T swapped: S^T[kv][q], kv=(r&3)+8*(r>>2)+4*hi, q=ln ----
    f32x16 s;
#pragma unroll
    for (int e = 0; e < 16; ++e) s[e] = 0.0f;
    const char* ksb = (const char*)Ks[cur];
    __builtin_amdgcn_s_setprio(1);
#pragma unroll
    for (int ks = 0; ks < 8; ++ks) {
      bf16x8 k0 = *(const bf16x8*)(ksb + (ln << 8) + ((ks * 32 + hi * 16) ^ ksw));
      s = __builtin_amdgcn_mfma_f32_32x32x16_bf16(k0, aq[ks], s, 0, 0, 0);
    }
    __builtin_amdgcn_s_setprio(0);

    // ---- softmax: p = exp2(s + mk*L2E); mask from LDS (swizzled rows) ----
    const char* msb = (const char*)Ms[cur] + ln * 128;
    unsigned own[8];
    float psum = 0.0f;
#pragma unroll
    for (int gq = 0; gq < 4; ++gq) {
      float4 mkq = *(const float4*)(msb + ((gq * 32 + hi * 16) ^ msw));
      float p0 = __builtin_exp2f(__builtin_fmaf(mkq.x, L2E, s[4 * gq + 0]));
      float p1 = __builtin_exp2f(__builtin_fmaf(mkq.y, L2E, s[4 * gq + 1]));
      float p2 = __builtin_exp2f(__builtin_fmaf(mkq.z, L2E, s[4 * gq + 2]));
      float p3 = __builtin_exp2f(__builtin_fmaf(mkq.w, L2E, s[4 * gq + 3]));
      psum += (p0 + p1) + (p2 + p3);
      own[2 * gq] = pk2(p0, p1);
      own[2 * gq + 1] = pk2(p2, p3);
    }
    lsum += psum;

    // ---- P B-frags via shfl_xor (verified): pf[ks][j]=P[q][ks*16+hi*8+j] ----
    unsigned sw[8];
#pragma unroll
    for (int i = 0; i < 8; ++i) sw[i] = __shfl_xor(own[i], 32);
    union Frag { unsigned u[4]; bf16x8 b; };
    Frag pf[2];
#pragma unroll
    for (int ks = 0; ks < 2; ++ks) {
      const int bsl = ks * 4;
      pf[ks].u[0] = hi ? sw[bsl + 2] : own[bsl + 0];
      pf[ks].u[1] = hi ? sw[bsl + 3] : own[bsl + 1];
      pf[ks].u[2] = hi ? own[bsl + 2] : sw[bsl + 0];
      pf[ks].u[3] = hi ? own[bsl + 3] : sw[bsl + 1];
    }

    // ---- PV swapped: O^T[d][q] += V^T · P ----
    const char* vtb = (const char*)Vt[cur];
    __builtin_amdgcn_s_setprio(1);
#pragma unroll
    for (int nt = 0; nt < 4; ++nt) {
      const int d = nt * 32 + ln;
      const int swz = (((d >> 3) ^ (d >> 1)) & 3) << 4;
#pragma unroll
      for (int ks = 0; ks < 2; ++ks) {
        bf16x8 vfr = *(const bf16x8*)(vtb + (d << 6) + (((ks * 32 + hi * 16)) ^ swz));
        o[nt] = __builtin_amdgcn_mfma_f32_32x32x16_bf16(vfr, pf[ks].b, o[nt], 0, 0, 0);
      }
    }
    __builtin_amdgcn_s_setprio(0);

    // one barrier per tile; drains vmcnt (gll for t+1 done) + lgkmcnt
    __syncthreads();
  }

  // ---- epilogue: O^T/l, write context[q][b][h*128+d] ----
  const float ltot = lsum + __shfl_xor(lsum, 32);
  const float invl = 1.0f / ltot;
  float* outp = Og + (size_t)(qb + ln) * (Bn * Hn * Dn) + (size_t)b * (Hn * Dn) + h * Dn;
#pragma unroll
  for (int nt = 0; nt < 4; ++nt)
#pragma unroll
    for (int gq = 0; gq < 4; ++gq) {
      float4 v;
      v.x = o[nt][gq * 4 + 0] * invl;
      v.y = o[nt][gq * 4 + 1] * invl;
      v.z = o[nt][gq * 4 + 2] * invl;
      v.w = o[nt][gq * 4 + 3] * invl;
      *(float4*)(outp + nt * 32 + gq * 8 + hi * 4) = v;
    }
}

extern "C" void kernel_launch(void* const* d_in, const int* in_sizes, int n_in,
                              void* d_out, int out_size, void* d_ws, size_t ws_size,
                              hipStream_t stream) {
  const float* q = (const float*)d_in[0];
  const float* k = (const float*)d_in[1];
  const float* v = (const float*)d_in[2];
  const float* m = (const float*)d_in[3];
  float* out = (float*)d_out;
  char* wsK = (char*)d_ws;
  char* wsV = wsK + WSK_BYTES;

  prepack<<<dim3((Bn * Gn * KVn * 64) / 256), 256, 0, stream>>>(k, v, wsK, wsV);
  dim3 grid(Qn / QBLK, Hn / HO, Bn);
  attn_fwd<<<grid, WAVES * 64, 0, stream>>>(q, m, wsK, wsV, out);
}

// Round 13
// 229.831 us; speedup vs baseline: 1.7050x; 1.7050x over previous
//
#include <hip/hip_runtime.h>
#include <hip/hip_bf16.h>

// CoreAttention (ChatGLM GQA fallback) — swapped-operand 32x32x16 bf16 MFMA
// flash attention. Round 13: r12 head-OCTET structure (8 waves = 8 heads
// sharing K/V/mask tiles) with launch_bounds(512,2): r12's (512,4) made the
// allocator clamp to 64 VGPR -> scratch spill catastrophe (FETCH 73->206MB).
// (512,2) caps at 256; natural ~105 VGPR lands in the <=128 tier => HW runs
// 4 waves/SIMD anyway (LDS 40KB x 2 blocks fits).
// B=2, H=32, G=2, Q=KV=2048, D=128, fp32 in/out.

constexpr int Bn = 2, Hn = 32, Gn = 2, Qn = 2048, KVn = 2048, Dn = 128;
constexpr int WAVES = 8, QBLK = 32, HO = 8;           // 32 q rows, 8 heads/blk
constexpr int KVB = 32, NT = KVn / KVB;               // 64 kv tiles
constexpr int NT32 = KVn / 32;
constexpr float SCALE = 0.08838834764831843f;         // 1/sqrt(128)
constexpr float L2E = 1.4426950408889634f;
constexpr float SCALE2 = SCALE * L2E;

// ws: K images (2 MiB) then V images (2 MiB); needs ws >= 4 MiB.
constexpr size_t WSK_BYTES = (size_t)Bn * Gn * KVn * 256;   // 2 MiB

typedef __attribute__((ext_vector_type(16))) float f32x16;
typedef __attribute__((ext_vector_type(8))) __bf16 bf16x8;

__device__ __forceinline__ unsigned pk2(float a, float b) {
  union { __bf16 h[2]; unsigned u; } x;
  x.h[0] = (__bf16)a; x.h[1] = (__bf16)b;
  return x.u;
}

__global__ __launch_bounds__(256)
void prepack(const float* __restrict__ Kg, const float* __restrict__ Vg,
             char* __restrict__ wsK, char* __restrict__ wsV) {
  const int i = blockIdx.x * 256 + threadIdx.x;   // [0, 524288)
  {  // K pair: dp = d/2
    const int dp = i & 63, kv = (i >> 6) & (KVn - 1), bg = i >> 17;
    const float* src = Kg + ((size_t)bg * KVn + kv) * Dn + 2 * dp;
    const unsigned pr = pk2(src[0], src[1]);
    const size_t off = (size_t)bg * (KVn * 256) + (size_t)kv * 256
                       + ((4 * dp) ^ ((kv & 15) << 4));
    *(unsigned*)(wsK + off) = pr;
  }
  {  // V^T pair: (kv=2vkp, 2vkp+1) at row d, 32-kv subtile t
    const int d = i & 127, vg = (i >> 7) & 1023, bg = i >> 17;
    const int t = vg >> 4, vkp = vg & 15;
    const float* src = Vg + ((size_t)bg * KVn + t * 32 + 2 * vkp) * Dn + d;
    const unsigned pr = pk2(src[0], src[Dn]);
    const int slot = (((d >> 3) ^ (d >> 1)) & 3) << 4;
    const size_t off = ((size_t)bg * NT32 + t) * 8192 + (d << 6)
                       + ((vkp * 4) ^ slot);
    *(unsigned*)(wsV + off) = pr;
  }
}

__global__ __launch_bounds__(512, 2)
void attn_fwd(const float* __restrict__ Qg, const float* __restrict__ Mg,
              const char* __restrict__ wsK, const char* __restrict__ wsV,
              float* __restrict__ Og) {
  __shared__ __align__(16) short Ks[2][KVB * Dn];    // 8KB x2
  __shared__ __align__(16) short Vt[2][Dn * KVB];    // 8KB x2
  __shared__ __align__(16) float Ms[2][QBLK * KVB];  // 4KB x2 (swizzled rows)

  const int tid = threadIdx.x;
  const int lane = tid & 63, w = tid >> 6;           // w in [0,8)
  const int hi = lane >> 5, ln = lane & 31;
  const int qb = blockIdx.x * QBLK, ho = blockIdx.y, b = blockIdx.z;
  const int h = ho * HO + w;                         // wave's head
  const int g = ho >> 1, bg = b * Gn + g;            // octet shares g

  // ---- Q B-fragments, PRE-SCALED: aq[ks][j] = Q[h][qb+ln][ks*16+hi*8+j]*SCALE2
  bf16x8 aq[8];
  {
    const float* qr = Qg + ((size_t)(b * Hn + h) * Qn + qb + ln) * Dn + hi * 8;
#pragma unroll
    for (int ks = 0; ks < 8; ++ks) {
      float4 f0 = *(const float4*)(qr + ks * 16);
      float4 f1 = *(const float4*)(qr + ks * 16 + 4);
      union { unsigned u[4]; bf16x8 b; } t;
      t.u[0] = pk2(f0.x * SCALE2, f0.y * SCALE2);
      t.u[1] = pk2(f0.z * SCALE2, f0.w * SCALE2);
      t.u[2] = pk2(f1.x * SCALE2, f1.y * SCALE2);
      t.u[3] = pk2(f1.z * SCALE2, f1.w * SCALE2);
      aq[ks] = t.b;
    }
  }

  const char* wsKb = wsK + (size_t)bg * (KVn * 256);
  const char* wsVb = wsV + (size_t)bg * (KVn * 256);
  // mask stage geometry (waves 0-3): wave w covers rows w*8..w*8+7 (128B each)
  const int mr = (w & 3) * 8 + (lane >> 3);          // q row within tile
  const int mc = (lane & 7) << 4;                    // 16B slot within row
  const char* mSrcBase = (const char*)Mg + (size_t)(b * Qn + qb + mr) * (KVn * 4)
                         + (mc ^ ((mr & 7) << 4));   // pre-swizzled source

  // waves 0-3: K (2 gll) + mask (1 gll); waves 4-7: V (2 gll)
  auto stage = [&](int tile, int buf) {
    if (w < 4) {
      const char* sk = wsKb + (size_t)tile * 8192 + w * 2048 + lane * 16;
      char* dk = (char*)Ks[buf] + w * 2048;
      __builtin_amdgcn_global_load_lds(
          (const __attribute__((address_space(1))) void*)sk,
          (__attribute__((address_space(3))) void*)dk, 16, 0, 0);
      __builtin_amdgcn_global_load_lds(
          (const __attribute__((address_space(1))) void*)(sk + 1024),
          (__attribute__((address_space(3))) void*)(dk + 1024), 16, 0, 0);
      const char* sm = mSrcBase + tile * 128;
      char* dm = (char*)Ms[buf] + w * 1024;
      __builtin_amdgcn_global_load_lds(
          (const __attribute__((address_space(1))) void*)sm,
          (__attribute__((address_space(3))) void*)dm, 16, 0, 0);
    } else {
      const int wv = w - 4;
      const char* sv = wsVb + (size_t)tile * 8192 + wv * 2048 + lane * 16;
      char* dv = (char*)Vt[buf] + wv * 2048;
      __builtin_amdgcn_global_load_lds(
          (const __attribute__((address_space(1))) void*)sv,
          (__attribute__((address_space(3))) void*)dv, 16, 0, 0);
      __builtin_amdgcn_global_load_lds(
          (const __attribute__((address_space(1))) void*)(sv + 1024),
          (__attribute__((address_space(3))) void*)(dv + 1024), 16, 0, 0);
    }
  };

  f32x16 o[4];
#pragma unroll
  for (int nt = 0; nt < 4; ++nt)
#pragma unroll
    for (int e = 0; e < 16; ++e) o[nt][e] = 0.0f;
  float lsum = 0.0f;

  // ---- prologue ----
  stage(0, 0);
  __syncthreads();

  const int ksw = (ln & 15) << 4;
  const int msw = (ln & 7) << 4;

  for (int t = 0; t < NT; ++t) {
    const int cur = t & 1;
    const int tn = (t + 1 < NT) ? t + 1 : t;

    stage(tn, cur ^ 1);     // prefetch next tile (gll; covered by tile body)
    __builtin_amdgcn_sched_barrier(0);

    // ---- QK^T swapped: S^T[kv][q], kv=(r&3)+8*(r>>2)+4*hi, q=ln ----
    f32x16 s;
#pragma unroll
    for (int e = 0; e < 16; ++e) s[e] = 0.0f;
    const char* ksb = (const char*)Ks[cur];
    __builtin_amdgcn_s_setprio(1);
#pragma unroll
    for (int ks = 0; ks < 8; ++ks) {
      bf16x8 k0 = *(const bf16x8*)(ksb + (ln << 8) + ((ks * 32 + hi * 16) ^ ksw));
      s = __builtin_amdgcn_mfma_f32_32x32x16_bf16(k0, aq[ks], s, 0, 0, 0);
    }
    __builtin_amdgcn_s_setprio(0);

    // ---- softmax: p = exp2(s + mk*L2E); mask from LDS (swizzled rows) ----
    const char* msb = (const char*)Ms[cur] + ln * 128;
    unsigned own[8];
    float psum = 0.0f;
#pragma unroll
    for (int gq = 0; gq < 4; ++gq) {
      float4 mkq = *(const float4*)(msb + ((gq * 32 + hi * 16) ^ msw));
      float p0 = __builtin_exp2f(__builtin_fmaf(mkq.x, L2E, s[4 * gq + 0]));
      float p1 = __builtin_exp2f(__builtin_fmaf(mkq.y, L2E, s[4 * gq + 1]));
      float p2 = __builtin_exp2f(__builtin_fmaf(mkq.z, L2E, s[4 * gq + 2]));
      float p3 = __builtin_exp2f(__builtin_fmaf(mkq.w, L2E, s[4 * gq + 3]));
      psum += (p0 + p1) + (p2 + p3);
      own[2 * gq] = pk2(p0, p1);
      own[2 * gq + 1] = pk2(p2, p3);
    }
    lsum += psum;

    // ---- P B-frags via shfl_xor (verified): pf[ks][j]=P[q][ks*16+hi*8+j] ----
    unsigned sw[8];
#pragma unroll
    for (int i = 0; i < 8; ++i) sw[i] = __shfl_xor(own[i], 32);
    union Frag { unsigned u[4]; bf16x8 b; };
    Frag pf[2];
#pragma unroll
    for (int ks = 0; ks < 2; ++ks) {
      const int bsl = ks * 4;
      pf[ks].u[0] = hi ? sw[bsl + 2] : own[bsl + 0];
      pf[ks].u[1] = hi ? sw[bsl + 3] : own[bsl + 1];
      pf[ks].u[2] = hi ? own[bsl + 2] : sw[bsl + 0];
      pf[ks].u[3] = hi ? own[bsl + 3] : sw[bsl + 1];
    }

    // ---- PV swapped: O^T[d][q] += V^T · P ----
    const char* vtb = (const char*)Vt[cur];
    __builtin_amdgcn_s_setprio(1);
#pragma unroll
    for (int nt = 0; nt < 4; ++nt) {
      const int d = nt * 32 + ln;
      const int swz = (((d >> 3) ^ (d >> 1)) & 3) << 4;
#pragma unroll
      for (int ks = 0; ks < 2; ++ks) {
        bf16x8 vfr = *(const bf16x8*)(vtb + (d << 6) + (((ks * 32 + hi * 16)) ^ swz));
        o[nt] = __builtin_amdgcn_mfma_f32_32x32x16_bf16(vfr, pf[ks].b, o[nt], 0, 0, 0);
      }
    }
    __builtin_amdgcn_s_setprio(0);

    // one barrier per tile; drains vmcnt (gll for t+1 done) + lgkmcnt
    __syncthreads();
  }

  // ---- epilogue: O^T/l, write context[q][b][h*128+d] ----
  const float ltot = lsum + __shfl_xor(lsum, 32);
  const float invl = 1.0f / ltot;
  float* outp = Og + (size_t)(qb + ln) * (Bn * Hn * Dn) + (size_t)b * (Hn * Dn) + h * Dn;
#pragma unroll
  for (int nt = 0; nt < 4; ++nt)
#pragma unroll
    for (int gq = 0; gq < 4; ++gq) {
      float4 v;
      v.x = o[nt][gq * 4 + 0] * invl;
      v.y = o[nt][gq * 4 + 1] * invl;
      v.z = o[nt][gq * 4 + 2] * invl;
      v.w = o[nt][gq * 4 + 3] * invl;
      *(float4*)(outp + nt * 32 + gq * 8 + hi * 4) = v;
    }
}

extern "C" void kernel_launch(void* const* d_in, const int* in_sizes, int n_in,
                              void* d_out, int out_size, void* d_ws, size_t ws_size,
                              hipStream_t stream) {
  const float* q = (const float*)d_in[0];
  const float* k = (const float*)d_in[1];
  const float* v = (const float*)d_in[2];
  const float* m = (const float*)d_in[3];
  float* out = (float*)d_out;
  char* wsK = (char*)d_ws;
  char* wsV = wsK + WSK_BYTES;

  prepack<<<dim3((Bn * Gn * KVn * 64) / 256), 256, 0, stream>>>(k, v, wsK, wsV);
  dim3 grid(Qn / QBLK, Hn / HO, Bn);
  attn_fwd<<<grid, WAVES * 64, 0, stream>>>(q, m, wsK, wsV, out);
}